// Round 6
// baseline (560.916 us; speedup 1.0000x reference)
//
#include <hip/hip_runtime.h>
#include <stdint.h>

#define HID 128
#define NNODES 50000
#define NEDGES 800000
#define WPL 98304  // bf16 weight elems per layer in wt scratch
#define PB 256     // nodes per placement bucket
#define NBK 196    // buckets (196*256 = 50176 padded nodes)

typedef __attribute__((ext_vector_type(8))) short short8;
typedef __attribute__((ext_vector_type(4))) float floatx4;

__device__ __forceinline__ float bf2f(unsigned short h) {
    union { unsigned int u; float f; } v; v.u = ((unsigned int)h) << 16; return v.f;
}
__device__ __forceinline__ unsigned short f2bf(float f) {
    union { float f; unsigned int u; } v; v.f = f;
    unsigned int u = v.u;
    return (unsigned short)((u + 0x7fffu + ((u >> 16) & 1u)) >> 16);
}

// ---- convert all layer weights to bf16, transposed to [n][k] for MFMA B-frags ----
// layout per layer l: [W1a^T 128x128 | W1b^T 128x128 | W2^T 128x128 | U1^T 128x256 | U2^T 128x128]
__global__ __launch_bounds__(256) void cvt_weights(
    const float* __restrict__ mW1, const float* __restrict__ mW2,
    const float* __restrict__ uW1, const float* __restrict__ uW2,
    unsigned short* __restrict__ wt)
{
    int id = blockIdx.x * 256 + threadIdx.x;
    int l = id / WPL;
    int r = id - l * WPL;
    float v;
    if (r < 16384)      { int n = r >> 7, k = r & 127;                v = mW1[(l*257 + k)*128 + n]; }
    else if (r < 32768) { int q = r - 16384; int n = q >> 7, k = q & 127; v = mW1[(l*257 + 128 + k)*128 + n]; }
    else if (r < 49152) { int q = r - 32768; int n = q >> 7, k = q & 127; v = mW2[(l*128 + k)*128 + n]; }
    else if (r < 81920) { int q = r - 49152; int n = q >> 8, k = q & 255; v = uW1[(l*256 + k)*128 + n]; }
    else                { int q = r - 81920; int n = q >> 7, k = q & 127; v = uW2[(l*128 + k)*128 + n]; }
    wt[id] = f2bf(v);
}

// ---- encoder: x0 = node_feat @ enc_W + enc_b, write bf16 into u_in[:,0:128] ----
__global__ __launch_bounds__(256) void encoder_k(
    const float* __restrict__ nf, const float* __restrict__ W,
    const float* __restrict__ b, unsigned short* __restrict__ u_in)
{
    int id = blockIdx.x * 256 + threadIdx.x;   // exact: 50000*128 threads
    int n = id >> 7, c = id & 127;
    float acc = b[c];
    #pragma unroll
    for (int k = 0; k < 5; ++k) acc += nf[n*5 + k] * W[k*128 + c];
    u_in[n*256 + c] = f2bf(acc);
}

// ---- CSR build ----
__global__ __launch_bounds__(256) void hist_k(const int* __restrict__ dst, int* __restrict__ cnt) {
    int e = blockIdx.x * 256 + threadIdx.x;
    atomicAdd(&cnt[dst[e]], 1);
}

__global__ __launch_bounds__(256) void scan1_k(const int* __restrict__ cnt,
                                               int* __restrict__ offs, int* __restrict__ btot)
{
    __shared__ int wsum[4];
    int tid = threadIdx.x, lane = tid & 63, wave = tid >> 6;
    int gid = blockIdx.x * 256 + tid;
    int4 v = ((const int4*)cnt)[gid];
    int tot = v.x + v.y + v.z + v.w;
    int sc = tot;
    #pragma unroll
    for (int o = 1; o < 64; o <<= 1) {
        int t = __shfl_up(sc, o);
        if (lane >= o) sc += t;
    }
    if (lane == 63) wsum[wave] = sc;
    __syncthreads();
    int woff = 0;
    #pragma unroll
    for (int i = 0; i < 3; ++i) if (i < wave) woff += wsum[i];
    int excl = woff + sc - tot;
    int4 o;
    o.x = excl; o.y = excl + v.x; o.z = o.y + v.y; o.w = o.z + v.z;
    ((int4*)offs)[gid] = o;
    if (tid == 255) btot[blockIdx.x] = woff + sc;
}

// merged scan2+3: each block reduces btot[0..blockIdx) itself, adds to its offs chunk
__global__ __launch_bounds__(256) void scan23_k(const int* __restrict__ btot, int* __restrict__ offs)
{
    __shared__ int psh;
    int tid = threadIdx.x;
    if (tid < 64) {
        int v = (tid < blockIdx.x) ? btot[tid] : 0;   // blockIdx < 49
        #pragma unroll
        for (int o = 32; o > 0; o >>= 1) v += __shfl_down(v, o);
        if (tid == 0) psh = v;
    }
    __syncthreads();
    int gid = blockIdx.x * 256 + tid;
    int p = psh;
    int4 o = ((int4*)offs)[gid];
    o.x += p; o.y += p; o.z += p; o.w += p;
    ((int4*)offs)[gid] = o;
}

// ---- bucketed placement: one block owns a 256-node dst range; scans all edges;
//      LDS cursors; writes land in the block's private contiguous CSR region
//      -> per-XCD L2 can merge them (fix for the 8x write amplification). ----
__global__ __launch_bounds__(1024) void place_k(
    const int* __restrict__ src, const int* __restrict__ dst,
    const float* __restrict__ ea, const int* __restrict__ offs,
    int2* __restrict__ sorted)
{
    __shared__ int cur[PB];
    int base = blockIdx.x * PB;
    if (threadIdx.x < PB) cur[threadIdx.x] = offs[base + threadIdx.x];
    __syncthreads();
    const int4* dst4 = (const int4*)dst;
    for (int i = threadIdx.x; i < NEDGES/4; i += 1024) {
        int4 d4 = dst4[i];
        int e0 = i * 4;
        int dv[4] = {d4.x, d4.y, d4.z, d4.w};
        #pragma unroll
        for (int u = 0; u < 4; ++u) {
            unsigned r = (unsigned)(dv[u] - base);
            if (r < PB) {
                int pos = atomicAdd(&cur[r], 1);
                int e = e0 + u;
                int2 pr; pr.x = src[e]; pr.y = __float_as_int(ea[e]);
                sorted[pos] = pr;
            }
        }
    }
}

// ---- per-node aggregation, 4x unrolled edge loop (4 independent gather chains) ----
// PQ layout: [50048][256] bf16, cols 0:128 = P (x@W1a+b1), cols 128:256 = Q (x@W1b)
__global__ __launch_bounds__(256) void aggregate_k(
    const unsigned short* __restrict__ PQ,
    const int2* __restrict__ sorted, const int* __restrict__ offs, const int* __restrict__ cnt,
    const float* __restrict__ w1c, unsigned short* __restrict__ Hb)
{
    int wave = threadIdx.x >> 6, lane = threadIdx.x & 63;
    int n = blockIdx.x * 4 + wave;      // grid exactly covers 50000
    int i0 = lane * 2;
    float2 w = *(const float2*)(w1c + i0);
    ushort2 p2 = *(const ushort2*)(PQ + (long)n*256 + i0);
    float p0 = bf2f(p2.x), p1 = bf2f(p2.y);
    int s = offs[n], c = cnt[n];
    const unsigned short* Qb = PQ + 128 + i0;
    float a00 = 0.f, a01 = 0.f, a10 = 0.f, a11 = 0.f;
    float a20 = 0.f, a21 = 0.f, a30 = 0.f, a31 = 0.f;
    int j = 0;
    for (; j + 4 <= c; j += 4) {
        int2 e0 = sorted[s+j], e1 = sorted[s+j+1], e2 = sorted[s+j+2], e3 = sorted[s+j+3];
        ushort2 q0 = *(const ushort2*)(Qb + (long)e0.x*256);
        ushort2 q1 = *(const ushort2*)(Qb + (long)e1.x*256);
        ushort2 q2 = *(const ushort2*)(Qb + (long)e2.x*256);
        ushort2 q3 = *(const ushort2*)(Qb + (long)e3.x*256);
        float v0 = __int_as_float(e0.y), v1 = __int_as_float(e1.y);
        float v2 = __int_as_float(e2.y), v3 = __int_as_float(e3.y);
        a00 += fmaxf(p0 + bf2f(q0.x) + v0*w.x, 0.f);
        a01 += fmaxf(p1 + bf2f(q0.y) + v0*w.y, 0.f);
        a10 += fmaxf(p0 + bf2f(q1.x) + v1*w.x, 0.f);
        a11 += fmaxf(p1 + bf2f(q1.y) + v1*w.y, 0.f);
        a20 += fmaxf(p0 + bf2f(q2.x) + v2*w.x, 0.f);
        a21 += fmaxf(p1 + bf2f(q2.y) + v2*w.y, 0.f);
        a30 += fmaxf(p0 + bf2f(q3.x) + v3*w.x, 0.f);
        a31 += fmaxf(p1 + bf2f(q3.y) + v3*w.y, 0.f);
    }
    for (; j < c; ++j) {
        int2 e0 = sorted[s+j];
        ushort2 q0 = *(const ushort2*)(Qb + (long)e0.x*256);
        float v0 = __int_as_float(e0.y);
        a00 += fmaxf(p0 + bf2f(q0.x) + v0*w.x, 0.f);
        a01 += fmaxf(p1 + bf2f(q0.y) + v0*w.y, 0.f);
    }
    float a0 = (a00 + a10) + (a20 + a30);
    float a1 = (a01 + a11) + (a21 + a31);
    float inv = 1.0f / fmaxf((float)c, 1.0f);
    ushort2 o; o.x = f2bf(a0 * inv); o.y = f2bf(a1 * inv);
    *(ushort2*)(Hb + (long)n*128 + i0) = o;
}

// ---- standalone MFMA GEMM (only used for the initial PQ0 = x0 @ [W1a|W1b] + b1) ----
__global__ __launch_bounds__(256) void gemm_pq_k(
    const unsigned short* __restrict__ A, int lda,
    const unsigned short* __restrict__ Bt,   // [256][128]
    const float* __restrict__ bias,          // first 128 cols only
    unsigned short* __restrict__ C, int ldc, int M, int K)
{
    __shared__ unsigned short As[64][72];
    __shared__ unsigned short Bs[256][72];
    int tid = threadIdx.x;
    int wave = tid >> 6, lane = tid & 63;
    int row0 = blockIdx.x * 64;
    floatx4 zero = {0.f, 0.f, 0.f, 0.f};
    floatx4 acc[16];
    #pragma unroll
    for (int t = 0; t < 16; ++t) acc[t] = zero;

    for (int k0 = 0; k0 < K; k0 += 64) {
        #pragma unroll
        for (int it = 0; it < 4; ++it) {
            int idx = it*1024 + tid*4;
            int r = idx >> 6, c = idx & 63;
            *(ushort4*)(&As[r][c]) = *(const ushort4*)(A + (long)(row0 + r)*lda + k0 + c);
        }
        #pragma unroll
        for (int it = 0; it < 16; ++it) {
            int idx = it*1024 + tid*4;
            int r = idx >> 6, c = idx & 63;
            *(ushort4*)(&Bs[r][c]) = *(const ushort4*)(Bt + (long)r*K + k0 + c);
        }
        __syncthreads();
        #pragma unroll
        for (int kk = 0; kk < 64; kk += 32) {
            short8 af = *(const short8*)(&As[wave*16 + (lane & 15)][kk + (lane >> 4)*8]);
            #pragma unroll
            for (int t = 0; t < 16; ++t) {
                short8 bf = *(const short8*)(&Bs[t*16 + (lane & 15)][kk + (lane >> 4)*8]);
                acc[t] = __builtin_amdgcn_mfma_f32_16x16x32_bf16(af, bf, acc[t], 0, 0, 0);
            }
        }
        __syncthreads();
    }
    int col_lane = lane & 15;
    int rbase = row0 + wave*16 + (lane >> 4)*4;
    #pragma unroll
    for (int t = 0; t < 16; ++t) {
        int col = t*16 + col_lane;
        float bv = (col < 128) ? bias[col] : 0.f;
        #pragma unroll
        for (int r = 0; r < 4; ++r) {
            int grow = rbase + r;
            if (grow < M) C[(long)grow*ldc + col] = f2bf(acc[t][r] + bv);
        }
    }
}

// ---- fused per-layer update: aggr=Hb@W2 -> u_hid=relu([x|aggr]@U1) -> x'=relu(LN(u_hid@U2))
//      -> PQ' = x'@W1ab[l+1] + b1'  (or, on the last layer, column-sum x' into sumv) ----
__global__ __launch_bounds__(256) void fused_update_k(
    const unsigned short* __restrict__ Hb,      // [50048][128]
    const unsigned short* __restrict__ w2t,     // [128][128]
    const unsigned short* __restrict__ u1t,     // [128][256]
    const unsigned short* __restrict__ u2t,     // [128][128]
    const unsigned short* __restrict__ w1abt,   // [256][128] next-layer, or null
    const float* __restrict__ mb2, const int* __restrict__ cnt,
    const float* __restrict__ ub1, const float* __restrict__ ub2,
    const float* __restrict__ lng, const float* __restrict__ lnb,
    const float* __restrict__ mb1n,             // next-layer b1, or null
    unsigned short* __restrict__ u_in,          // x at stride 256 (read cols 0:128, write x')
    unsigned short* __restrict__ PQ,            // [50048][256] out (if w1abt)
    float* __restrict__ sumv)                   // [128] colsum out (if !w1abt)
{
    __shared__ unsigned short As[64][72];
    __shared__ unsigned short Bs[128][72];
    __shared__ unsigned short buf[64][136];     // inter-stage A operand (aggr/u_hid/x')
    int tid = threadIdx.x;
    int wave = tid >> 6, lane = tid & 63;
    int col_lane = lane & 15, quad = lane >> 4;
    int row0 = blockIdx.x * 64;
    int lrow_base = wave*16 + quad*4;           // local row base in C-layout
    floatx4 zero = {0.f, 0.f, 0.f, 0.f};
    floatx4 acc[8];

#define STAGE_A(ptr, stride, k0) { _Pragma("unroll") \
    for (int it = 0; it < 4; ++it) { int idx = it*1024 + tid*4; int r = idx >> 6, c = idx & 63; \
        *(ushort4*)(&As[r][c]) = *(const ushort4*)((ptr) + (long)(row0 + r)*(stride) + (k0) + c); } }
#define STAGE_B(ptr, stride, k0) { _Pragma("unroll") \
    for (int it = 0; it < 8; ++it) { int idx = it*1024 + tid*4; int r = idx >> 6, c = idx & 63; \
        *(ushort4*)(&Bs[r][c]) = *(const ushort4*)((ptr) + (long)r*(stride) + (k0) + c); } }
#define MFMA_AS() { _Pragma("unroll") for (int kk = 0; kk < 64; kk += 32) { \
    short8 af = *(const short8*)(&As[wave*16 + col_lane][kk + quad*8]); \
    _Pragma("unroll") for (int t = 0; t < 8; ++t) { \
        short8 bf = *(const short8*)(&Bs[t*16 + col_lane][kk + quad*8]); \
        acc[t] = __builtin_amdgcn_mfma_f32_16x16x32_bf16(af, bf, acc[t], 0, 0, 0); } } }
#define MFMA_BUF(k0) { _Pragma("unroll") for (int kk = 0; kk < 64; kk += 32) { \
    short8 af = *(const short8*)(&buf[wave*16 + col_lane][(k0) + kk + quad*8]); \
    _Pragma("unroll") for (int t = 0; t < 8; ++t) { \
        short8 bf = *(const short8*)(&Bs[t*16 + col_lane][kk + quad*8]); \
        acc[t] = __builtin_amdgcn_mfma_f32_16x16x32_bf16(af, bf, acc[t], 0, 0, 0); } } }

    // ---------- step 1: aggr = Hb@W2 + mb2*[deg>0] -> buf ----------
    #pragma unroll
    for (int t = 0; t < 8; ++t) acc[t] = zero;
    for (int k0 = 0; k0 < 128; k0 += 64) {
        STAGE_A(Hb, 128, k0);
        STAGE_B(w2t, 128, k0);
        __syncthreads();
        MFMA_AS();
        __syncthreads();
    }
    float maskr[4];
    #pragma unroll
    for (int r = 0; r < 4; ++r) maskr[r] = (cnt[row0 + lrow_base + r] > 0) ? 1.f : 0.f;
    #pragma unroll
    for (int t = 0; t < 8; ++t) {
        int col = t*16 + col_lane;
        float bv = mb2[col];
        #pragma unroll
        for (int r = 0; r < 4; ++r)
            buf[lrow_base + r][col] = f2bf(acc[t][r] + bv * maskr[r]);
    }
    __syncthreads();

    // ---------- step 2: u_hid = relu(x@U1a + aggr@U1b + ub1) -> buf ----------
    #pragma unroll
    for (int t = 0; t < 8; ++t) acc[t] = zero;
    for (int k0 = 0; k0 < 128; k0 += 64) {       // x part (global), U1 k-cols 0..128
        STAGE_A(u_in, 256, k0);
        STAGE_B(u1t, 256, k0);
        __syncthreads();
        MFMA_AS();
        __syncthreads();
    }
    for (int k0 = 0; k0 < 128; k0 += 64) {       // aggr part (LDS), U1 k-cols 128..256
        STAGE_B(u1t, 256, 128 + k0);
        __syncthreads();
        MFMA_BUF(k0);
        __syncthreads();
    }
    #pragma unroll
    for (int t = 0; t < 8; ++t) {
        int col = t*16 + col_lane;
        float bv = ub1[col];
        #pragma unroll
        for (int r = 0; r < 4; ++r)
            buf[lrow_base + r][col] = f2bf(fmaxf(acc[t][r] + bv, 0.f));
    }
    __syncthreads();

    // ---------- step 3: y = u_hid@U2 + ub2 ; x' = relu(LN(y)*g+b) -> global + buf ----------
    #pragma unroll
    for (int t = 0; t < 8; ++t) acc[t] = zero;
    for (int k0 = 0; k0 < 128; k0 += 64) {
        STAGE_B(u2t, 128, k0);
        __syncthreads();
        MFMA_BUF(k0);
        __syncthreads();
    }
    {
        float rowsum[4] = {0.f,0.f,0.f,0.f}, rowsq[4] = {0.f,0.f,0.f,0.f};
        #pragma unroll
        for (int t = 0; t < 8; ++t) {
            float bv = ub2[t*16 + col_lane];
            #pragma unroll
            for (int r = 0; r < 4; ++r) {
                acc[t][r] += bv;
                rowsum[r] += acc[t][r];
                rowsq[r]  += acc[t][r]*acc[t][r];
            }
        }
        #pragma unroll
        for (int o = 1; o < 16; o <<= 1) {
            #pragma unroll
            for (int r = 0; r < 4; ++r) {
                rowsum[r] += __shfl_xor(rowsum[r], o);
                rowsq[r]  += __shfl_xor(rowsq[r], o);
            }
        }
        float mu[4], rs[4];
        #pragma unroll
        for (int r = 0; r < 4; ++r) {
            mu[r] = rowsum[r] * (1.f/128.f);
            float var = rowsq[r] * (1.f/128.f) - mu[r]*mu[r];
            rs[r] = rsqrtf(var + 1e-5f);
        }
        float colacc[8];
        #pragma unroll
        for (int t = 0; t < 8; ++t) {
            int col = t*16 + col_lane;
            float gv = lng[col], bb = lnb[col];
            float s = 0.f;
            #pragma unroll
            for (int r = 0; r < 4; ++r) {
                float y = fmaxf((acc[t][r] - mu[r]) * rs[r] * gv + bb, 0.f);
                unsigned short h = f2bf(y);
                int grow = row0 + lrow_base + r;
                if (grow < NNODES) { u_in[(long)grow*256 + col] = h; s += y; }
                buf[lrow_base + r][col] = h;
            }
            colacc[t] = s;
        }
        if (!w1abt) {
            // column-sum of x' into sumv (replaces the standalone colsum kernel)
            #pragma unroll
            for (int t = 0; t < 8; ++t) {
                colacc[t] += __shfl_xor(colacc[t], 16);
                colacc[t] += __shfl_xor(colacc[t], 32);
            }
            float* red = (float*)&As[0][0];     // As is free here: 4*128 floats = 2 KB
            __syncthreads();
            if (lane < 16) {
                #pragma unroll
                for (int t = 0; t < 8; ++t) red[wave*128 + t*16 + lane] = colacc[t];
            }
            __syncthreads();
            if (tid < 128) {
                float s = red[tid] + red[128 + tid] + red[256 + tid] + red[384 + tid];
                atomicAdd(&sumv[tid], s);
            }
        }
    }

    // ---------- step 4: PQ' = x'@W1ab' (+b1' on P half) ----------
    if (w1abt) {
        __syncthreads();
        #pragma unroll
        for (int half = 0; half < 2; ++half) {
            #pragma unroll
            for (int t = 0; t < 8; ++t) acc[t] = zero;
            for (int k0 = 0; k0 < 128; k0 += 64) {
                STAGE_B(w1abt + (long)half*128*128, 128, k0);
                __syncthreads();
                MFMA_BUF(k0);
                __syncthreads();
            }
            #pragma unroll
            for (int t = 0; t < 8; ++t) {
                int col = t*16 + col_lane;
                float bv = (half == 0) ? mb1n[col] : 0.f;
                #pragma unroll
                for (int r = 0; r < 4; ++r) {
                    int grow = row0 + lrow_base + r;
                    PQ[(long)grow*256 + half*128 + col] = f2bf(acc[t][r] + bv);
                }
            }
        }
    }
#undef STAGE_A
#undef STAGE_B
#undef MFMA_AS
#undef MFMA_BUF
}

// ---- final tiny MLP on the mean (fp32) ----
__global__ __launch_bounds__(128) void final_k(
    const float* __restrict__ sum, const float* __restrict__ W1, const float* __restrict__ b1,
    const float* __restrict__ W2, const float* __restrict__ b2, float* __restrict__ out)
{
    __shared__ float gbuf[128], hbuf[128];
    int t = threadIdx.x;
    gbuf[t] = sum[t] * (1.f / 50000.f);
    __syncthreads();
    float a = b1[t];
    for (int k = 0; k < 128; ++k) a += gbuf[k] * W1[k*128 + t];
    hbuf[t] = fmaxf(a, 0.f);
    __syncthreads();
    float o = b2[t];
    for (int k = 0; k < 128; ++k) o += hbuf[k] * W2[k*128 + t];
    out[t] = o;
}

extern "C" void kernel_launch(void* const* d_in, const int* in_sizes, int n_in,
                              void* d_out, int out_size, void* d_ws, size_t ws_size,
                              hipStream_t stream)
{
    const float* node_feat = (const float*)d_in[0];
    const float* edge_attr = (const float*)d_in[1];
    const float* enc_W  = (const float*)d_in[2];
    const float* enc_b  = (const float*)d_in[3];
    const float* mlp_W1 = (const float*)d_in[4];
    const float* mlp_b1 = (const float*)d_in[5];
    const float* mlp_W2 = (const float*)d_in[6];
    const float* mlp_b2 = (const float*)d_in[7];
    const float* upd_W1 = (const float*)d_in[8];
    const float* upd_b1 = (const float*)d_in[9];
    const float* upd_W2 = (const float*)d_in[10];
    const float* upd_b2 = (const float*)d_in[11];
    const float* ln_g   = (const float*)d_in[12];
    const float* ln_b   = (const float*)d_in[13];
    const float* out_W1 = (const float*)d_in[14];
    const float* out_b1 = (const float*)d_in[15];
    const float* out_W2 = (const float*)d_in[16];
    const float* out_b2 = (const float*)d_in[17];
    const int* edge_index = (const int*)d_in[18];
    const int* e_src = edge_index;
    const int* e_dst = edge_index + NEDGES;

    // workspace layout (padded node rows = 50048; scan arrays padded to 50176 = 49*1024)
    char* ws = (char*)d_ws;
    unsigned short* u_in = (unsigned short*)(ws + 0);          // [50048][256] bf16: [x | scratch]
    unsigned short* PQ   = (unsigned short*)(ws + 25624576);   // [50048][256] bf16: [P | Q]
    unsigned short* Hb   = (unsigned short*)(ws + 51249152);   // [50048][128] bf16
    int2* sorted         = (int2*)(ws + 64061440);             // [800000] {src, ea}
    int* cnt             = (int*)(ws + 70461440);              // [50176]
    int* offs            = (int*)(ws + 70662144);              // [50176]
    int* btot            = (int*)(ws + 71063552);              // [64]
    unsigned short* wt   = (unsigned short*)(ws + 71064064);   // [3*WPL] bf16 weights
    float* sumv          = (float*)(ws + 71653888);            // [128]

    hipMemsetAsync(cnt, 0, 50176*4, stream);
    hipMemsetAsync(sumv, 0, 512, stream);
    cvt_weights<<<1152, 256, 0, stream>>>(mlp_W1, mlp_W2, upd_W1, upd_W2, wt);
    encoder_k<<<25000, 256, 0, stream>>>(node_feat, enc_W, enc_b, u_in);
    hist_k<<<3125, 256, 0, stream>>>(e_dst, cnt);
    scan1_k<<<49, 256, 0, stream>>>(cnt, offs, btot);
    scan23_k<<<49, 256, 0, stream>>>(btot, offs);
    place_k<<<NBK, 1024, 0, stream>>>(e_src, e_dst, edge_attr, offs, sorted);

    // PQ0 = x0 @ [W1a|W1b] + b1 (layer 0 weights)
    gemm_pq_k<<<782, 256, 0, stream>>>(u_in, 256, wt, mlp_b1, PQ, 256, NNODES, 128);

    for (int l = 0; l < 3; ++l) {
        const unsigned short* w2t = wt + l*WPL + 32768;    // [128][128]
        const unsigned short* u1t = wt + l*WPL + 49152;    // [128][256]
        const unsigned short* u2t = wt + l*WPL + 81920;    // [128][128]
        // Hb = inv_deg * segsum(relu(P[dst]+Q[src]+ea*w1c))
        aggregate_k<<<12500, 256, 0, stream>>>(PQ, sorted, offs, cnt,
                                               mlp_W1 + (l*257 + 256)*128, Hb);
        // fused: aggr -> u_hid -> x' (LN) -> PQ for layer l+1 (or colsum on last layer)
        fused_update_k<<<782, 256, 0, stream>>>(
            Hb, w2t, u1t, u2t,
            (l < 2) ? (wt + (l+1)*WPL) : nullptr,
            mlp_b2 + l*128, cnt,
            upd_b1 + l*128, upd_b2 + l*128,
            ln_g + l*128, ln_b + l*128,
            (l < 2) ? (mlp_b1 + (l+1)*128) : nullptr,
            u_in, PQ, sumv);
    }
    final_k<<<1, 128, 0, stream>>>(sumv, out_W1, out_b1, out_W2, out_b2, (float*)d_out);
}

// Round 7
// 478.029 us; speedup vs baseline: 1.1734x; 1.1734x over previous
//
#include <hip/hip_runtime.h>
#include <stdint.h>

#define HID 128
#define NNODES 50000
#define NEDGES 800000
#define WPL 98304   // bf16 weight elems per layer in wt scratch
#define NPAD 50176  // padded node count (= 196*256 = 49*1024)
#define DRNG 6272   // dst-range per XCD group (50176/8)

typedef __attribute__((ext_vector_type(8))) short short8;
typedef __attribute__((ext_vector_type(4))) float floatx4;

__device__ __forceinline__ float bf2f(unsigned short h) {
    union { unsigned int u; float f; } v; v.u = ((unsigned int)h) << 16; return v.f;
}
__device__ __forceinline__ unsigned short f2bf(float f) {
    union { float f; unsigned int u; } v; v.f = f;
    unsigned int u = v.u;
    return (unsigned short)((u + 0x7fffu + ((u >> 16) & 1u)) >> 16);
}

// ---- convert all layer weights to bf16, transposed to [n][k] for MFMA B-frags ----
// layout per layer l: [W1a^T 128x128 | W1b^T 128x128 | W2^T 128x128 | U1^T 128x256 | U2^T 128x128]
__global__ __launch_bounds__(256) void cvt_weights(
    const float* __restrict__ mW1, const float* __restrict__ mW2,
    const float* __restrict__ uW1, const float* __restrict__ uW2,
    unsigned short* __restrict__ wt)
{
    int id = blockIdx.x * 256 + threadIdx.x;
    int l = id / WPL;
    int r = id - l * WPL;
    float v;
    if (r < 16384)      { int n = r >> 7, k = r & 127;                v = mW1[(l*257 + k)*128 + n]; }
    else if (r < 32768) { int q = r - 16384; int n = q >> 7, k = q & 127; v = mW1[(l*257 + 128 + k)*128 + n]; }
    else if (r < 49152) { int q = r - 32768; int n = q >> 7, k = q & 127; v = mW2[(l*128 + k)*128 + n]; }
    else if (r < 81920) { int q = r - 49152; int n = q >> 8, k = q & 255; v = uW1[(l*256 + k)*128 + n]; }
    else                { int q = r - 81920; int n = q >> 7, k = q & 127; v = uW2[(l*128 + k)*128 + n]; }
    wt[id] = f2bf(v);
}

// ---- encoder: x0 = node_feat @ enc_W + enc_b, write bf16 into u_in[:,0:128] ----
__global__ __launch_bounds__(256) void encoder_k(
    const float* __restrict__ nf, const float* __restrict__ W,
    const float* __restrict__ b, unsigned short* __restrict__ u_in)
{
    int id = blockIdx.x * 256 + threadIdx.x;   // exact: 50000*128 threads
    int n = id >> 7, c = id & 127;
    float acc = b[c];
    #pragma unroll
    for (int k = 0; k < 5; ++k) acc += nf[n*5 + k] * W[k*128 + c];
    u_in[n*256 + c] = f2bf(acc);
}

// ---- CSR build ----
__global__ __launch_bounds__(256) void hist_k(const int* __restrict__ dst, int* __restrict__ cnt) {
    int e = blockIdx.x * 256 + threadIdx.x;
    atomicAdd(&cnt[dst[e]], 1);
}

__global__ __launch_bounds__(256) void scan1_k(const int* __restrict__ cnt,
                                               int* __restrict__ offs, int* __restrict__ btot)
{
    __shared__ int wsum[4];
    int tid = threadIdx.x, lane = tid & 63, wave = tid >> 6;
    int gid = blockIdx.x * 256 + tid;
    int4 v = ((const int4*)cnt)[gid];
    int tot = v.x + v.y + v.z + v.w;
    int sc = tot;
    #pragma unroll
    for (int o = 1; o < 64; o <<= 1) {
        int t = __shfl_up(sc, o);
        if (lane >= o) sc += t;
    }
    if (lane == 63) wsum[wave] = sc;
    __syncthreads();
    int woff = 0;
    #pragma unroll
    for (int i = 0; i < 3; ++i) if (i < wave) woff += wsum[i];
    int excl = woff + sc - tot;
    int4 o;
    o.x = excl; o.y = excl + v.x; o.z = o.y + v.y; o.w = o.z + v.z;
    ((int4*)offs)[gid] = o;
    if (tid == 255) btot[blockIdx.x] = woff + sc;
}

// merged scan2+3: each block reduces btot[0..blockIdx) itself, adds to offs + cursor
__global__ __launch_bounds__(256) void scan23_k(const int* __restrict__ btot,
                                                int* __restrict__ offs, int* __restrict__ cursor)
{
    __shared__ int psh;
    int tid = threadIdx.x;
    if (tid < 64) {
        int v = (tid < blockIdx.x) ? btot[tid] : 0;   // blockIdx < 49
        #pragma unroll
        for (int o = 32; o > 0; o >>= 1) v += __shfl_down(v, o);
        if (tid == 0) psh = v;
    }
    __syncthreads();
    int gid = blockIdx.x * 256 + tid;
    int p = psh;
    int4 o = ((int4*)offs)[gid];
    o.x += p; o.y += p; o.z += p; o.w += p;
    ((int4*)offs)[gid] = o;
    ((int4*)cursor)[gid] = o;
}

// ---- XCD-partitioned scatter placement ----
// group g = blockIdx&7 (round-robin block->XCD heuristic) handles dst in [g*DRNG, (g+1)*DRNG):
// each `sorted` cache line is then written by ONE XCD only -> partial-line writebacks collapse
// from 8 copies/line to 1. Record packed to 4 B {bf16 ea | u16 src} (NNODES < 65536).
__global__ __launch_bounds__(256) void place_k(
    const int* __restrict__ src, const int* __restrict__ dst,
    const float* __restrict__ ea, int* __restrict__ cursor,
    unsigned int* __restrict__ sorted)
{
    int g = blockIdx.x & 7;
    int rank = blockIdx.x >> 3;          // 391 ranks cover 391*2048 >= NEDGES
    int lo = g * DRNG;
    int base = rank * 2048 + threadIdx.x * 8;
    if (base >= NEDGES) return;          // NEDGES % 8 == 0: all-or-nothing per thread
    const int4* d4 = (const int4*)(dst + base);
    int4 a = d4[0], b = d4[1];
    int dv[8] = {a.x, a.y, a.z, a.w, b.x, b.y, b.z, b.w};
    #pragma unroll
    for (int u = 0; u < 8; ++u) {
        unsigned r = (unsigned)(dv[u] - lo);
        if (r < DRNG) {
            int e = base + u;
            int pos = atomicAdd(&cursor[dv[u]], 1);
            unsigned pr = ((unsigned)f2bf(ea[e]) << 16) | (unsigned)src[e];
            sorted[pos] = pr;
        }
    }
}

// ---- per-node aggregation, 4x unrolled edge loop (4 independent gather chains) ----
// PQ layout: [50048][256] bf16, cols 0:128 = P (x@W1a+b1), cols 128:256 = Q (x@W1b)
__global__ __launch_bounds__(256) void aggregate_k(
    const unsigned short* __restrict__ PQ,
    const unsigned int* __restrict__ sorted, const int* __restrict__ offs,
    const int* __restrict__ cnt,
    const float* __restrict__ w1c, unsigned short* __restrict__ Hb)
{
    int wave = threadIdx.x >> 6, lane = threadIdx.x & 63;
    int n = blockIdx.x * 4 + wave;      // grid exactly covers 50000
    int i0 = lane * 2;
    float2 w = *(const float2*)(w1c + i0);
    ushort2 p2 = *(const ushort2*)(PQ + (long)n*256 + i0);
    float p0 = bf2f(p2.x), p1 = bf2f(p2.y);
    int s = offs[n], c = cnt[n];
    const unsigned short* Qb = PQ + 128 + i0;
    float a00 = 0.f, a01 = 0.f, a10 = 0.f, a11 = 0.f;
    float a20 = 0.f, a21 = 0.f, a30 = 0.f, a31 = 0.f;
    int j = 0;
    for (; j + 4 <= c; j += 4) {
        unsigned e0 = sorted[s+j], e1 = sorted[s+j+1], e2 = sorted[s+j+2], e3 = sorted[s+j+3];
        ushort2 q0 = *(const ushort2*)(Qb + (long)(e0 & 0xffffu)*256);
        ushort2 q1 = *(const ushort2*)(Qb + (long)(e1 & 0xffffu)*256);
        ushort2 q2 = *(const ushort2*)(Qb + (long)(e2 & 0xffffu)*256);
        ushort2 q3 = *(const ushort2*)(Qb + (long)(e3 & 0xffffu)*256);
        float v0 = bf2f((unsigned short)(e0 >> 16)), v1 = bf2f((unsigned short)(e1 >> 16));
        float v2 = bf2f((unsigned short)(e2 >> 16)), v3 = bf2f((unsigned short)(e3 >> 16));
        a00 += fmaxf(p0 + bf2f(q0.x) + v0*w.x, 0.f);
        a01 += fmaxf(p1 + bf2f(q0.y) + v0*w.y, 0.f);
        a10 += fmaxf(p0 + bf2f(q1.x) + v1*w.x, 0.f);
        a11 += fmaxf(p1 + bf2f(q1.y) + v1*w.y, 0.f);
        a20 += fmaxf(p0 + bf2f(q2.x) + v2*w.x, 0.f);
        a21 += fmaxf(p1 + bf2f(q2.y) + v2*w.y, 0.f);
        a30 += fmaxf(p0 + bf2f(q3.x) + v3*w.x, 0.f);
        a31 += fmaxf(p1 + bf2f(q3.y) + v3*w.y, 0.f);
    }
    for (; j < c; ++j) {
        unsigned e0 = sorted[s+j];
        ushort2 q0 = *(const ushort2*)(Qb + (long)(e0 & 0xffffu)*256);
        float v0 = bf2f((unsigned short)(e0 >> 16));
        a00 += fmaxf(p0 + bf2f(q0.x) + v0*w.x, 0.f);
        a01 += fmaxf(p1 + bf2f(q0.y) + v0*w.y, 0.f);
    }
    float a0 = (a00 + a10) + (a20 + a30);
    float a1 = (a01 + a11) + (a21 + a31);
    float inv = 1.0f / fmaxf((float)c, 1.0f);
    ushort2 o; o.x = f2bf(a0 * inv); o.y = f2bf(a1 * inv);
    *(ushort2*)(Hb + (long)n*128 + i0) = o;
}

// ---- standalone MFMA GEMM (only used for the initial PQ0 = x0 @ [W1a|W1b] + b1) ----
__global__ __launch_bounds__(256) void gemm_pq_k(
    const unsigned short* __restrict__ A, int lda,
    const unsigned short* __restrict__ Bt,   // [256][128]
    const float* __restrict__ bias,          // first 128 cols only
    unsigned short* __restrict__ C, int ldc, int M, int K)
{
    __shared__ unsigned short As[64][72];
    __shared__ unsigned short Bs[256][72];
    int tid = threadIdx.x;
    int wave = tid >> 6, lane = tid & 63;
    int row0 = blockIdx.x * 64;
    floatx4 zero = {0.f, 0.f, 0.f, 0.f};
    floatx4 acc[16];
    #pragma unroll
    for (int t = 0; t < 16; ++t) acc[t] = zero;

    for (int k0 = 0; k0 < K; k0 += 64) {
        #pragma unroll
        for (int it = 0; it < 4; ++it) {
            int idx = it*1024 + tid*4;
            int r = idx >> 6, c = idx & 63;
            *(ushort4*)(&As[r][c]) = *(const ushort4*)(A + (long)(row0 + r)*lda + k0 + c);
        }
        #pragma unroll
        for (int it = 0; it < 16; ++it) {
            int idx = it*1024 + tid*4;
            int r = idx >> 6, c = idx & 63;
            *(ushort4*)(&Bs[r][c]) = *(const ushort4*)(Bt + (long)r*K + k0 + c);
        }
        __syncthreads();
        #pragma unroll
        for (int kk = 0; kk < 64; kk += 32) {
            short8 af = *(const short8*)(&As[wave*16 + (lane & 15)][kk + (lane >> 4)*8]);
            #pragma unroll
            for (int t = 0; t < 16; ++t) {
                short8 bf = *(const short8*)(&Bs[t*16 + (lane & 15)][kk + (lane >> 4)*8]);
                acc[t] = __builtin_amdgcn_mfma_f32_16x16x32_bf16(af, bf, acc[t], 0, 0, 0);
            }
        }
        __syncthreads();
    }
    int col_lane = lane & 15;
    int rbase = row0 + wave*16 + (lane >> 4)*4;
    #pragma unroll
    for (int t = 0; t < 16; ++t) {
        int col = t*16 + col_lane;
        float bv = (col < 128) ? bias[col] : 0.f;
        #pragma unroll
        for (int r = 0; r < 4; ++r) {
            int grow = rbase + r;
            if (grow < M) C[(long)grow*ldc + col] = f2bf(acc[t][r] + bv);
        }
    }
}

// ---- fused per-layer update: aggr=Hb@W2 -> u_hid=relu([x|aggr]@U1) -> x'=relu(LN(u_hid@U2))
//      -> PQ' = x'@W1ab[l+1] + b1'  (or, on the last layer, column-sum x' into sumv) ----
__global__ __launch_bounds__(256) void fused_update_k(
    const unsigned short* __restrict__ Hb,      // [50048][128]
    const unsigned short* __restrict__ w2t,     // [128][128]
    const unsigned short* __restrict__ u1t,     // [128][256]
    const unsigned short* __restrict__ u2t,     // [128][128]
    const unsigned short* __restrict__ w1abt,   // [256][128] next-layer, or null
    const float* __restrict__ mb2, const int* __restrict__ cnt,
    const float* __restrict__ ub1, const float* __restrict__ ub2,
    const float* __restrict__ lng, const float* __restrict__ lnb,
    const float* __restrict__ mb1n,             // next-layer b1, or null
    unsigned short* __restrict__ u_in,          // x at stride 256 (read cols 0:128, write x')
    unsigned short* __restrict__ PQ,            // [50048][256] out (if w1abt)
    float* __restrict__ sumv)                   // [128] colsum out (if !w1abt)
{
    __shared__ unsigned short As[64][72];
    __shared__ unsigned short Bs[128][72];
    __shared__ unsigned short buf[64][136];     // inter-stage A operand (aggr/u_hid/x')
    int tid = threadIdx.x;
    int wave = tid >> 6, lane = tid & 63;
    int col_lane = lane & 15, quad = lane >> 4;
    int row0 = blockIdx.x * 64;
    int lrow_base = wave*16 + quad*4;           // local row base in C-layout
    floatx4 zero = {0.f, 0.f, 0.f, 0.f};
    floatx4 acc[8];

#define STAGE_A(ptr, stride, k0) { _Pragma("unroll") \
    for (int it = 0; it < 4; ++it) { int idx = it*1024 + tid*4; int r = idx >> 6, c = idx & 63; \
        *(ushort4*)(&As[r][c]) = *(const ushort4*)((ptr) + (long)(row0 + r)*(stride) + (k0) + c); } }
#define STAGE_B(ptr, stride, k0) { _Pragma("unroll") \
    for (int it = 0; it < 8; ++it) { int idx = it*1024 + tid*4; int r = idx >> 6, c = idx & 63; \
        *(ushort4*)(&Bs[r][c]) = *(const ushort4*)((ptr) + (long)r*(stride) + (k0) + c); } }
#define MFMA_AS() { _Pragma("unroll") for (int kk = 0; kk < 64; kk += 32) { \
    short8 af = *(const short8*)(&As[wave*16 + col_lane][kk + quad*8]); \
    _Pragma("unroll") for (int t = 0; t < 8; ++t) { \
        short8 bf = *(const short8*)(&Bs[t*16 + col_lane][kk + quad*8]); \
        acc[t] = __builtin_amdgcn_mfma_f32_16x16x32_bf16(af, bf, acc[t], 0, 0, 0); } } }
#define MFMA_BUF(k0) { _Pragma("unroll") for (int kk = 0; kk < 64; kk += 32) { \
    short8 af = *(const short8*)(&buf[wave*16 + col_lane][(k0) + kk + quad*8]); \
    _Pragma("unroll") for (int t = 0; t < 8; ++t) { \
        short8 bf = *(const short8*)(&Bs[t*16 + col_lane][kk + quad*8]); \
        acc[t] = __builtin_amdgcn_mfma_f32_16x16x32_bf16(af, bf, acc[t], 0, 0, 0); } } }

    // ---------- step 1: aggr = Hb@W2 + mb2*[deg>0] -> buf ----------
    #pragma unroll
    for (int t = 0; t < 8; ++t) acc[t] = zero;
    for (int k0 = 0; k0 < 128; k0 += 64) {
        STAGE_A(Hb, 128, k0);
        STAGE_B(w2t, 128, k0);
        __syncthreads();
        MFMA_AS();
        __syncthreads();
    }
    float maskr[4];
    #pragma unroll
    for (int r = 0; r < 4; ++r) maskr[r] = (cnt[row0 + lrow_base + r] > 0) ? 1.f : 0.f;
    #pragma unroll
    for (int t = 0; t < 8; ++t) {
        int col = t*16 + col_lane;
        float bv = mb2[col];
        #pragma unroll
        for (int r = 0; r < 4; ++r)
            buf[lrow_base + r][col] = f2bf(acc[t][r] + bv * maskr[r]);
    }
    __syncthreads();

    // ---------- step 2: u_hid = relu(x@U1a + aggr@U1b + ub1) -> buf ----------
    #pragma unroll
    for (int t = 0; t < 8; ++t) acc[t] = zero;
    for (int k0 = 0; k0 < 128; k0 += 64) {       // x part (global), U1 k-cols 0..128
        STAGE_A(u_in, 256, k0);
        STAGE_B(u1t, 256, k0);
        __syncthreads();
        MFMA_AS();
        __syncthreads();
    }
    for (int k0 = 0; k0 < 128; k0 += 64) {       // aggr part (LDS), U1 k-cols 128..256
        STAGE_B(u1t, 256, 128 + k0);
        __syncthreads();
        MFMA_BUF(k0);
        __syncthreads();
    }
    #pragma unroll
    for (int t = 0; t < 8; ++t) {
        int col = t*16 + col_lane;
        float bv = ub1[col];
        #pragma unroll
        for (int r = 0; r < 4; ++r)
            buf[lrow_base + r][col] = f2bf(fmaxf(acc[t][r] + bv, 0.f));
    }
    __syncthreads();

    // ---------- step 3: y = u_hid@U2 + ub2 ; x' = relu(LN(y)*g+b) -> global + buf ----------
    #pragma unroll
    for (int t = 0; t < 8; ++t) acc[t] = zero;
    for (int k0 = 0; k0 < 128; k0 += 64) {
        STAGE_B(u2t, 128, k0);
        __syncthreads();
        MFMA_BUF(k0);
        __syncthreads();
    }
    {
        float rowsum[4] = {0.f,0.f,0.f,0.f}, rowsq[4] = {0.f,0.f,0.f,0.f};
        #pragma unroll
        for (int t = 0; t < 8; ++t) {
            float bv = ub2[t*16 + col_lane];
            #pragma unroll
            for (int r = 0; r < 4; ++r) {
                acc[t][r] += bv;
                rowsum[r] += acc[t][r];
                rowsq[r]  += acc[t][r]*acc[t][r];
            }
        }
        #pragma unroll
        for (int o = 1; o < 16; o <<= 1) {
            #pragma unroll
            for (int r = 0; r < 4; ++r) {
                rowsum[r] += __shfl_xor(rowsum[r], o);
                rowsq[r]  += __shfl_xor(rowsq[r], o);
            }
        }
        float mu[4], rs[4];
        #pragma unroll
        for (int r = 0; r < 4; ++r) {
            mu[r] = rowsum[r] * (1.f/128.f);
            float var = rowsq[r] * (1.f/128.f) - mu[r]*mu[r];
            rs[r] = rsqrtf(var + 1e-5f);
        }
        float colacc[8];
        #pragma unroll
        for (int t = 0; t < 8; ++t) {
            int col = t*16 + col_lane;
            float gv = lng[col], bb = lnb[col];
            float s = 0.f;
            #pragma unroll
            for (int r = 0; r < 4; ++r) {
                float y = fmaxf((acc[t][r] - mu[r]) * rs[r] * gv + bb, 0.f);
                unsigned short h = f2bf(y);
                int grow = row0 + lrow_base + r;
                if (grow < NNODES) { u_in[(long)grow*256 + col] = h; s += y; }
                buf[lrow_base + r][col] = h;
            }
            colacc[t] = s;
        }
        if (!w1abt) {
            // column-sum of x' into sumv (replaces the standalone colsum kernel)
            #pragma unroll
            for (int t = 0; t < 8; ++t) {
                colacc[t] += __shfl_xor(colacc[t], 16);
                colacc[t] += __shfl_xor(colacc[t], 32);
            }
            float* red = (float*)&As[0][0];     // As is free here: 4*128 floats = 2 KB
            __syncthreads();
            if (lane < 16) {
                #pragma unroll
                for (int t = 0; t < 8; ++t) red[wave*128 + t*16 + lane] = colacc[t];
            }
            __syncthreads();
            if (tid < 128) {
                float s = red[tid] + red[128 + tid] + red[256 + tid] + red[384 + tid];
                atomicAdd(&sumv[tid], s);
            }
        }
    }

    // ---------- step 4: PQ' = x'@W1ab' (+b1' on P half) ----------
    if (w1abt) {
        __syncthreads();
        #pragma unroll
        for (int half = 0; half < 2; ++half) {
            #pragma unroll
            for (int t = 0; t < 8; ++t) acc[t] = zero;
            for (int k0 = 0; k0 < 128; k0 += 64) {
                STAGE_B(w1abt + (long)half*128*128, 128, k0);
                __syncthreads();
                MFMA_BUF(k0);
                __syncthreads();
            }
            #pragma unroll
            for (int t = 0; t < 8; ++t) {
                int col = t*16 + col_lane;
                float bv = (half == 0) ? mb1n[col] : 0.f;
                #pragma unroll
                for (int r = 0; r < 4; ++r) {
                    int grow = row0 + lrow_base + r;
                    PQ[(long)grow*256 + half*128 + col] = f2bf(acc[t][r] + bv);
                }
            }
        }
    }
#undef STAGE_A
#undef STAGE_B
#undef MFMA_AS
#undef MFMA_BUF
}

// ---- final tiny MLP on the mean (fp32) ----
__global__ __launch_bounds__(128) void final_k(
    const float* __restrict__ sum, const float* __restrict__ W1, const float* __restrict__ b1,
    const float* __restrict__ W2, const float* __restrict__ b2, float* __restrict__ out)
{
    __shared__ float gbuf[128], hbuf[128];
    int t = threadIdx.x;
    gbuf[t] = sum[t] * (1.f / 50000.f);
    __syncthreads();
    float a = b1[t];
    for (int k = 0; k < 128; ++k) a += gbuf[k] * W1[k*128 + t];
    hbuf[t] = fmaxf(a, 0.f);
    __syncthreads();
    float o = b2[t];
    for (int k = 0; k < 128; ++k) o += hbuf[k] * W2[k*128 + t];
    out[t] = o;
}

extern "C" void kernel_launch(void* const* d_in, const int* in_sizes, int n_in,
                              void* d_out, int out_size, void* d_ws, size_t ws_size,
                              hipStream_t stream)
{
    const float* node_feat = (const float*)d_in[0];
    const float* edge_attr = (const float*)d_in[1];
    const float* enc_W  = (const float*)d_in[2];
    const float* enc_b  = (const float*)d_in[3];
    const float* mlp_W1 = (const float*)d_in[4];
    const float* mlp_b1 = (const float*)d_in[5];
    const float* mlp_W2 = (const float*)d_in[6];
    const float* mlp_b2 = (const float*)d_in[7];
    const float* upd_W1 = (const float*)d_in[8];
    const float* upd_b1 = (const float*)d_in[9];
    const float* upd_W2 = (const float*)d_in[10];
    const float* upd_b2 = (const float*)d_in[11];
    const float* ln_g   = (const float*)d_in[12];
    const float* ln_b   = (const float*)d_in[13];
    const float* out_W1 = (const float*)d_in[14];
    const float* out_b1 = (const float*)d_in[15];
    const float* out_W2 = (const float*)d_in[16];
    const float* out_b2 = (const float*)d_in[17];
    const int* edge_index = (const int*)d_in[18];
    const int* e_src = edge_index;
    const int* e_dst = edge_index + NEDGES;

    // workspace layout (padded node rows = 50048; scan arrays padded to 50176)
    char* ws = (char*)d_ws;
    unsigned short* u_in = (unsigned short*)(ws + 0);          // [50048][256] bf16: [x | scratch]
    unsigned short* PQ   = (unsigned short*)(ws + 25624576);   // [50048][256] bf16: [P | Q]
    unsigned short* Hb   = (unsigned short*)(ws + 51249152);   // [50048][128] bf16
    unsigned int* sorted = (unsigned int*)(ws + 64061440);     // [800000] packed {bf16 ea | u16 src}
    int* cnt             = (int*)(ws + 70461440);              // [50176]
    int* offs            = (int*)(ws + 70662144);              // [50176]
    int* cursor          = (int*)(ws + 70862848);              // [50176]
    int* btot            = (int*)(ws + 71063552);              // [64]
    unsigned short* wt   = (unsigned short*)(ws + 71064064);   // [3*WPL] bf16 weights
    float* sumv          = (float*)(ws + 71653888);            // [128]

    hipMemsetAsync(cnt, 0, NPAD*4, stream);
    hipMemsetAsync(sumv, 0, 512, stream);
    cvt_weights<<<1152, 256, 0, stream>>>(mlp_W1, mlp_W2, upd_W1, upd_W2, wt);
    encoder_k<<<25000, 256, 0, stream>>>(node_feat, enc_W, enc_b, u_in);
    hist_k<<<3125, 256, 0, stream>>>(e_dst, cnt);
    scan1_k<<<49, 256, 0, stream>>>(cnt, offs, btot);
    scan23_k<<<49, 256, 0, stream>>>(btot, offs, cursor);
    place_k<<<3128, 256, 0, stream>>>(e_src, e_dst, edge_attr, cursor, sorted);

    // PQ0 = x0 @ [W1a|W1b] + b1 (layer 0 weights)
    gemm_pq_k<<<782, 256, 0, stream>>>(u_in, 256, wt, mlp_b1, PQ, 256, NNODES, 128);

    for (int l = 0; l < 3; ++l) {
        const unsigned short* w2t = wt + l*WPL + 32768;    // [128][128]
        const unsigned short* u1t = wt + l*WPL + 49152;    // [128][256]
        const unsigned short* u2t = wt + l*WPL + 81920;    // [128][128]
        // Hb = inv_deg * segsum(relu(P[dst]+Q[src]+ea*w1c))
        aggregate_k<<<12500, 256, 0, stream>>>(PQ, sorted, offs, cnt,
                                               mlp_W1 + (l*257 + 256)*128, Hb);
        // fused: aggr -> u_hid -> x' (LN) -> PQ for layer l+1 (or colsum on last layer)
        fused_update_k<<<782, 256, 0, stream>>>(
            Hb, w2t, u1t, u2t,
            (l < 2) ? (wt + (l+1)*WPL) : nullptr,
            mlp_b2 + l*128, cnt,
            upd_b1 + l*128, upd_b2 + l*128,
            ln_g + l*128, ln_b + l*128,
            (l < 2) ? (mlp_b1 + (l+1)*128) : nullptr,
            u_in, PQ, sumv);
    }
    final_k<<<1, 128, 0, stream>>>(sumv, out_W1, out_b1, out_W2, out_b2, (float*)d_out);
}